// Round 8
// baseline (598.870 us; speedup 1.0000x reference)
//
#include <hip/hip_runtime.h>

// GlobalAttentionPooling: tensor_square_0e -> selu -> @W -> segment softmax -> weighted segment sum
// N nodes, 80 f32 ft (32 scalar + 16 x 3-vec), NG=1024 graphs (sorted batch_index), F=664.
//
// Math identities (validated rounds 1-4, absmax 3.9e-3):
//   selu const term cancels in softmax; pre-scale s by sqrt(log2e), v by sqrt(log2e/sqrt3)
//   so pair products are f*log2e -> exp2 directly. out_g = (sum nf*ex)/z_g.
//
// Round-13: ABLATION SPLIT. After 6 probes the fused main_kernel is pinned at
//   wall = ~31us VALU + ~50us stall, and the stall is invariant to code size (r7/r9),
//   operand residency (r5/r8/r12: global-sunk vs LDS vs registers), exp method (r10 bounds
//   the trans pipe at <=8us), TPB/occupancy (r6/r12), VGPR budget (r12). Fused counters
//   aggregate phase 1 (compute+LDS) with phase 2 (atomics+gather) -- cannot attribute.
//   Split: p1_kernel = phase 1 verbatim from r12 (same codegen, VGPR~40), writes ex[] to ws;
//   p2_kernel = phase 2 verbatim r5-shape (320 nodes/block), reads ex/bi from global.
//   Readout: p1-dominant -> attack W path next (W is wave-uniform; unrolled indices are
//   compile-time -> s_load/SGPR operands instead of ds_read). p2-dominant -> rework segment
//   path. Cost bound: 1 extra launch + 2.4MB ex round-trip.

typedef float f2 __attribute__((ext_vector_type(2)));

#define C0 32
#define C1 16
#define NODE_F 80
#define NG_CONST 1024
#define TPB1 256                // p1: threads per block (1 thread/node)
#define NPB2 320                // p2: nodes per block
#define TPB2 320

#define SELU_SCALE 1.0507009873554804934193349852946
#define SELU_ALPHA 1.6732632423543772848170429916717
#define LOG2E      1.4426950408889634073599246810019

#define CS_SCALE 1.2011224087864498f    // sqrt(log2e)
#define CV_SCALE 0.91271231102878545f   // sqrt(log2e/sqrt(3))

// ws float layout:
//   [0, 81920)        S accum: [1024 graphs][80 ch]
//   [81920, 82944)    z accum: [1024]
//   [82944, 84224)    Wpad: 512 f2 scalar rows (32x16) then 128 f2 vec rows (16x8)
//   [84224, 84224+N)  exbuf
#define WS_S 0
#define WS_Z 81920
#define WS_W 82944
#define WS_EX 84224

__device__ __forceinline__ int ks_idx(int i, int j) { return i * C0 - (i * (i - 1)) / 2 + (j - i); }
__device__ __forceinline__ int kv_idx(int i, int j) { return 528 + i * C1 - (i * (i - 1)) / 2 + (j - i); }

// zero the accumulators + build padded W tables
__global__ __launch_bounds__(256) void prep_kernel(
    const float* __restrict__ W, float* __restrict__ ws)
{
    const int t = blockIdx.x * blockDim.x + threadIdx.x;
    if (t < 82944) {
        ws[t] = 0.0f;                       // S and z
    } else {
        int u = t - 82944;
        if (u < 512) {                      // Ws: i in [0,32), q in [0,16)
            int i = u >> 4, q = u & 15;
            int j0 = 2 * q, j1 = 2 * q + 1;
            ws[WS_W + 2 * u]     = (j0 >= i) ? W[ks_idx(i, j0)] : 0.0f;
            ws[WS_W + 2 * u + 1] = (j1 >= i) ? W[ks_idx(i, j1)] : 0.0f;
        } else if (u < 640) {               // Wv: i in [0,16), q in [0,8)
            int v = u - 512;
            int i = v >> 3, q = v & 7;
            int j0 = 2 * q, j1 = 2 * q + 1;
            ws[WS_W + 1024 + 2 * v]     = (j0 >= i) ? W[kv_idx(i, j0)] : 0.0f;
            ws[WS_W + 1024 + 2 * v + 1] = (j1 >= i) ? W[kv_idx(i, j1)] : 0.0f;
        }
    }
}

// ---- phase 1 standalone: attention logit -> ex, one thread per node ----
__global__ __launch_bounds__(TPB1, 4) void p1_kernel(
    const float* __restrict__ nf, const float* __restrict__ ws,
    float* __restrict__ exbuf, int N)
{
    __shared__ __align__(16) float Wlds[1280];

    const int tid  = threadIdx.x;
    const int n    = blockIdx.x * TPB1 + tid;
    const float4* g4 = (const float4*)nf;

    #pragma unroll
    for (int u = tid; u < 1280; u += TPB1) Wlds[u] = ws[WS_W + u];

    const bool valid = (n < N);
    const int  nn    = valid ? n : (N - 1);
    __syncthreads();                        // Wlds ready

    const float4* gp = g4 + (size_t)nn * 20;
    const f2* WsL = (const f2*)Wlds;          // 512 f2
    const f2* WvL = (const f2*)(Wlds + 1024); // 128 f2

    // scalar half -> s2 in registers, PINNED against load-sinking (r12 codegen)
    f2 s2[C0 / 2];
    {
        float4 rs[8];
        #pragma unroll
        for (int q = 0; q < 8; ++q) rs[q] = gp[q];
        #pragma unroll
        for (int q = 0; q < 8; ++q) {
            s2[2 * q]     = f2{rs[q].x, rs[q].y} * CS_SCALE;
            s2[2 * q + 1] = f2{rs[q].z, rs[q].w} * CS_SCALE;
        }
    }
    #pragma unroll
    for (int q = 0; q < C0 / 2; ++q) asm volatile("" : "+v"(s2[q]));

    f2 accA[2], accB[2];
    accA[0] = (f2)0.f; accA[1] = (f2)0.f; accB[0] = (f2)0.f; accB[1] = (f2)0.f;

    // scalar triangle rows 0..15
    #pragma unroll
    for (int i = 0; i < 16; ++i) {
        const float si = (i & 1) ? s2[i >> 1].y : s2[i >> 1].x;
        const f2 si2 = f2{si, si};
        #pragma unroll
        for (int q = i >> 1; q < C0 / 2; ++q) {
            f2 f = si2 * s2[q];
            f2 p = __builtin_elementwise_max(f, (f2)0.f);
            f2 m = __builtin_elementwise_min(f, (f2)0.f);
            f2 e; e.x = __builtin_amdgcn_exp2f(m.x);
                  e.y = __builtin_amdgcn_exp2f(m.y);
            f2 w = WsL[i * 16 + q];             // broadcast ds_read_b64, pad slots = 0
            accA[q & 1] = __builtin_elementwise_fma(w, p, accA[q & 1]);
            accB[q & 1] = __builtin_elementwise_fma(w, e, accB[q & 1]);
        }
    }

    // issue vector-half global loads; rows 16..31 cover their HBM latency
    float4 rv[12];
    #pragma unroll
    for (int q = 0; q < 12; ++q) rv[q] = gp[8 + q];

    // scalar triangle rows 16..31
    #pragma unroll
    for (int i = 16; i < 32; ++i) {
        const float si = (i & 1) ? s2[i >> 1].y : s2[i >> 1].x;
        const f2 si2 = f2{si, si};
        #pragma unroll
        for (int q = i >> 1; q < C0 / 2; ++q) {
            f2 f = si2 * s2[q];
            f2 p = __builtin_elementwise_max(f, (f2)0.f);
            f2 m = __builtin_elementwise_min(f, (f2)0.f);
            f2 e; e.x = __builtin_amdgcn_exp2f(m.x);
                  e.y = __builtin_amdgcn_exp2f(m.y);
            f2 w = WsL[i * 16 + q];
            accA[q & 1] = __builtin_elementwise_fma(w, p, accA[q & 1]);
            accB[q & 1] = __builtin_elementwise_fma(w, e, accB[q & 1]);
        }
    }

    // vector part: build vp (unpinned -- s2 dead here), triangle
    f2 vp[C1 / 2][3];
    {
        const float* rvf = (const float*)rv;
        #pragma unroll
        for (int q = 0; q < C1 / 2; ++q) {
            #pragma unroll
            for (int c = 0; c < 3; ++c)
                vp[q][c] = f2{rvf[6 * q + c], rvf[6 * q + 3 + c]} * CV_SCALE;
        }
    }

    #pragma unroll
    for (int i = 0; i < C1; ++i) {
        const int iq = i >> 1;
        const float vi0 = (i & 1) ? vp[iq][0].y : vp[iq][0].x;
        const float vi1 = (i & 1) ? vp[iq][1].y : vp[iq][1].x;
        const float vi2 = (i & 1) ? vp[iq][2].y : vp[iq][2].x;
        #pragma unroll
        for (int q = i >> 1; q < C1 / 2; ++q) {
            f2 f = vp[q][0] * f2{vi0, vi0};
            f = __builtin_elementwise_fma(vp[q][1], f2{vi1, vi1}, f);
            f = __builtin_elementwise_fma(vp[q][2], f2{vi2, vi2}, f);
            f2 p = __builtin_elementwise_max(f, (f2)0.f);
            f2 m = __builtin_elementwise_min(f, (f2)0.f);
            f2 e; e.x = __builtin_amdgcn_exp2f(m.x);
                  e.y = __builtin_amdgcn_exp2f(m.y);
            f2 w = WvL[i * 8 + q];
            accA[q & 1] = __builtin_elementwise_fma(w, p, accA[q & 1]);
            accB[q & 1] = __builtin_elementwise_fma(w, e, accB[q & 1]);
        }
    }

    const float A1 = accA[0].x + accA[0].y + accA[1].x + accA[1].y;
    const float A2 = accB[0].x + accB[0].y + accB[1].x + accB[1].y;
    const float l2 = fmaf((float)SELU_SCALE, A1,
                          (float)(SELU_SCALE * SELU_ALPHA * LOG2E) * A2);
    if (valid) exbuf[n] = __builtin_amdgcn_exp2f(l2);
}

// ---- phase 2 standalone: weighted segment sum, r5 shape (16 chunks x 20 cols x 20 nodes) ----
__global__ __launch_bounds__(TPB2, 2) void p2_kernel(
    const float* __restrict__ nf, const int* __restrict__ bi,
    const float* __restrict__ exbuf, float* __restrict__ S,
    float* __restrict__ z, int N)
{
    __shared__ float exl[NPB2];
    __shared__ int   bil[NPB2];

    const int tid  = threadIdx.x;
    const int base = blockIdx.x * NPB2;
    const float4* g4 = (const float4*)nf;

    const int idx0 = base + tid;
    bil[tid] = bi[idx0 > N - 1 ? N - 1 : idx0];
    exl[tid] = (idx0 < N) ? exbuf[idx0] : 0.0f;
    __syncthreads();

    const int no = tid / 20;       // 0..15
    const int c4 = tid % 20;
    int cg = bil[no * 20];
    float4 acc = make_float4(0.f, 0.f, 0.f, 0.f);
    float  zacc = 0.0f;

    #pragma unroll
    for (int k = 0; k < 20; ++k) {
        const int nl = no * 20 + k;
        const int g2 = bil[nl];
        if (g2 != cg) {
            unsafeAtomicAdd(&S[cg * NODE_F + c4 * 4 + 0], acc.x);
            unsafeAtomicAdd(&S[cg * NODE_F + c4 * 4 + 1], acc.y);
            unsafeAtomicAdd(&S[cg * NODE_F + c4 * 4 + 2], acc.z);
            unsafeAtomicAdd(&S[cg * NODE_F + c4 * 4 + 3], acc.w);
            if (c4 == 0) unsafeAtomicAdd(&z[cg], zacc);
            acc = make_float4(0.f, 0.f, 0.f, 0.f); zacc = 0.0f; cg = g2;
        }
        int idx = base + nl; if (idx > N - 1) idx = N - 1;   // pad nodes have w=0
        const float  w = exl[nl];
        const float4 v = g4[(size_t)idx * 20 + c4];
        acc.x = fmaf(v.x, w, acc.x); acc.y = fmaf(v.y, w, acc.y);
        acc.z = fmaf(v.z, w, acc.z); acc.w = fmaf(v.w, w, acc.w);
        zacc += w;
    }
    unsafeAtomicAdd(&S[cg * NODE_F + c4 * 4 + 0], acc.x);
    unsafeAtomicAdd(&S[cg * NODE_F + c4 * 4 + 1], acc.y);
    unsafeAtomicAdd(&S[cg * NODE_F + c4 * 4 + 2], acc.z);
    unsafeAtomicAdd(&S[cg * NODE_F + c4 * 4 + 3], acc.w);
    if (c4 == 0) unsafeAtomicAdd(&z[cg], zacc);
}

__global__ __launch_bounds__(256) void divide_kernel(
    const float* __restrict__ S, const float* __restrict__ z,
    float* __restrict__ out)
{
    const int t = blockIdx.x * blockDim.x + threadIdx.x;
    if (t >= NG_CONST * NODE_F) return;
    const float zz = z[t / NODE_F];
    out[t] = (zz > 0.0f) ? (S[t] / zz) : 0.0f;
}

extern "C" void kernel_launch(void* const* d_in, const int* in_sizes, int n_in,
                              void* d_out, int out_size, void* d_ws, size_t ws_size,
                              hipStream_t stream) {
    const float* nf = (const float*)d_in[0];   // (N, 80) f32
    const int*   bi = (const int*)d_in[1];     // (N,) i32 sorted
    // d_in[2] = num_graphs (static 1024)
    const float* W  = (const float*)d_in[3];   // (664,) f32
    float* out = (float*)d_out;

    const int N = in_sizes[0] / NODE_F;
    float* ws = (float*)d_ws;
    float* S  = ws + WS_S;
    float* z  = ws + WS_Z;
    float* ex = ws + WS_EX;

    hipLaunchKernelGGL(prep_kernel, dim3(332), dim3(256), 0, stream, W, ws);
    hipLaunchKernelGGL(p1_kernel, dim3((N + TPB1 - 1) / TPB1), dim3(TPB1), 0, stream,
                       nf, ws, ex, N);
    hipLaunchKernelGGL(p2_kernel, dim3((N + NPB2 - 1) / NPB2), dim3(TPB2), 0, stream,
                       nf, bi, ex, S, z, N);
    hipLaunchKernelGGL(divide_kernel, dim3((NG_CONST * NODE_F + 255) / 256), dim3(256),
                       0, stream, S, z, out);
}